// Round 6
// baseline (69.591 us; speedup 1.0000x reference)
//
#include <hip/hip_runtime.h>
#include <math.h>

// Problem constants
#define BATCH 4096
#define NFEAT 2048
#define NNEUR 1024
#define NTGT  8
#define NNZ1  65536
#define NNZ2  8192

// GEMM: h[m][n] = sigmoid( sum_k W1b[m][k] * xb[n][k] + b1[m] ), fused layer-2 partials
//   M = NNEUR (1024), N = BATCH (4096), K = NFEAT (2048)
// 128x64 tile, 256 threads (4 waves = 2m x 2n), grid 512 = 2 blocks/CU.
#define BM 128
#define BN 64
#define BK 32
#define KITERS (NFEAT / BK)

typedef short  bf16x8 __attribute__((ext_vector_type(8)));
typedef float  f32x4  __attribute__((ext_vector_type(4)));

// ---------------- workspace layout (bytes) ----------------
// W1f : [NNEUR][NFEAT] f32    8 MB     @ 0
// W2d : [NNEUR][NTGT] f32    32 KB     @ 8 MB        (zeroed together with W1f)
// W1b : [NNEUR][NFEAT] bf16   4 MB     @ 8 MB+32KB
// xb  : [BATCH][NFEAT] bf16  16 MB     @ 12 MB+32KB
// part: [8][BATCH][NTGT] f32  1 MB     @ 28 MB+32KB
#define OFF_W1F  ((size_t)0)
#define OFF_W2D  ((size_t)8388608)
#define OFF_W1B  ((size_t)8421376)
#define OFF_XB   ((size_t)12615680)
#define OFF_PART ((size_t)29392896)

// W1f + W2d are contiguous: 8421376 B = 526336 float4
#define ZERO_FLOAT4 526336

__device__ __forceinline__ unsigned short f2bf(float f) {
    union { float f; unsigned int u; } a; a.f = f;
    unsigned int u = a.u;
    u += 0x7fffu + ((u >> 16) & 1u);   // round-to-nearest-even
    return (unsigned short)(u >> 16);
}

__device__ __forceinline__ void load_lds16(const unsigned short* g, unsigned short* l) {
    __builtin_amdgcn_global_load_lds(
        (const __attribute__((address_space(1))) unsigned int*)g,
        (__attribute__((address_space(3))) unsigned int*)l,
        16, 0, 0);
}

// fast zero of W1f+W2d (rocclr fill kernel profiled at 200 GB/s on this size)
__global__ void k_zero4(float4* __restrict__ p) {
    int i = blockIdx.x * blockDim.x + threadIdx.x;
    p[i] = make_float4(0.f, 0.f, 0.f, 0.f);
}

// scatter-add edges into dense W1f and W2d (handles duplicate edges by summing)
__global__ void k_build(const float* __restrict__ w1, const int* __restrict__ c1o,
                        const int* __restrict__ c1i,
                        const float* __restrict__ w2, const int* __restrict__ c2o,
                        const int* __restrict__ c2i,
                        float* __restrict__ W1f, float* __restrict__ W2d) {
    int i = blockIdx.x * blockDim.x + threadIdx.x;
    if (i < NNZ1) {
        atomicAdd(&W1f[(size_t)c1o[i] * NFEAT + c1i[i]], w1[i]);
    } else {
        int j = i - NNZ1;
        if (j < NNZ2) atomicAdd(&W2d[c2i[j] * NTGT + c2o[j]], w2[j]);
    }
}

// convert W1f -> W1b and x -> xb, float4 -> 4x bf16 per thread
__global__ void k_convert(const float* __restrict__ W1f, const float* __restrict__ x,
                          unsigned short* __restrict__ W1b, unsigned short* __restrict__ xb) {
    int i = blockIdx.x * blockDim.x + threadIdx.x;
    const int nW = NNEUR * NFEAT / 4;
    const int nX = BATCH * NFEAT / 4;
    if (i < nW) {
        float4 v = ((const float4*)W1f)[i];
        ushort4 o;
        o.x = f2bf(v.x); o.y = f2bf(v.y); o.z = f2bf(v.z); o.w = f2bf(v.w);
        ((ushort4*)W1b)[i] = o;
    } else if (i < nW + nX) {
        int j = i - nW;
        float4 v = ((const float4*)x)[j];
        ushort4 o;
        o.x = f2bf(v.x); o.y = f2bf(v.y); o.z = f2bf(v.z); o.w = f2bf(v.w);
        ((ushort4*)xb)[j] = o;
    }
}

// bf16 MFMA GEMM with fused bias+sigmoid+layer2-partial epilogue.
// 128x64 tile, BK=32, double-buffered LDS, global_load_lds(16B) with
// pre-swizzled k-slot (bank-conflict-free ds_read_b128), ONE barrier per K-iter.
// 256 threads = 4 waves (2m x 2n); wave computes 64x32 via 4x2 frags of 16x16x32.
// Grid 512 = 2 blocks/CU: second block's waves hide the barrier drain (m114).
__global__ __launch_bounds__(256) void k_gemm(const unsigned short* __restrict__ W1b,
                                              const unsigned short* __restrict__ xb,
                                              const float* __restrict__ b1,
                                              const float* __restrict__ W2d,
                                              float* __restrict__ partial) {
    __shared__ unsigned short ldsA[2][BM * BK];   // 2 x 8 KB
    __shared__ unsigned short ldsB[2][BN * BK];   // 2 x 4 KB
    __shared__ float s_w2[BM][NTGT];              // 4 KB
    __shared__ float s_b1[BM];                    // 512 B
    __shared__ float s_pt[2][BN][NTGT];           // 4 KB

    // bijective XCD swizzle: each XCD gets 8 contiguous n-tiles x all 8 m-tiles;
    // m iterates fastest so W1b (4MB) stays L2-resident per XCD.
    int bid = blockIdx.x;                  // 0..511
    int v   = bid >> 3;                    // per-XCD index 0..63
    int n0  = ((bid & 7) * 8 + (v >> 3)) * BN;   // 64 n-tiles
    int mt  = v & 7;                       // 8 m-tiles
    int m0  = mt * BM;

    int tid  = threadIdx.x;
    int wv   = tid >> 6;
    int lane = tid & 63;
    int wm = wv >> 1, wn = wv & 1;         // wave grid 2m x 2n
    int lr = lane & 15, lg = lane >> 4;

    // preload W2d + b1 slices for the epilogue
    for (int i = tid; i < BM * NTGT; i += 256)
        s_w2[i >> 3][i & 7] = W2d[(m0 + (i >> 3)) * NTGT + (i & 7)];
    if (tid < BM) s_b1[tid] = b1[m0 + tid];

    f32x4 zero4 = {0.f, 0.f, 0.f, 0.f};
    f32x4 acc[4][2];
#pragma unroll
    for (int i = 0; i < 4; ++i)
#pragma unroll
        for (int j = 0; j < 2; ++j) acc[i][j] = zero4;

    // staging (linear LDS dest, pre-swizzled global k-slot; rule #21).
    // LDS unit u (16B) = row*4 + slot; global slot = (u&3) ^ ((u>>3)&3).
    // A tile = 512 units -> 2 calls (unit tid, tid+256); B tile = 256 units -> 1 call.
    int uA1 = tid + 256;
    const unsigned short* gA0 = &W1b[(size_t)(m0 + (tid >> 2)) * NFEAT + ((tid & 3) ^ ((tid >> 3) & 3)) * 8];
    const unsigned short* gA1 = &W1b[(size_t)(m0 + (uA1 >> 2)) * NFEAT + ((uA1 & 3) ^ ((uA1 >> 3) & 3)) * 8];
    const unsigned short* gB  = &xb [(size_t)(n0 + (tid >> 2)) * NFEAT + ((tid & 3) ^ ((tid >> 3) & 3)) * 8];
    // wave-uniform LDS bases (lane lands at +lane*16B)
    const int baseA0 = (wv * 64) * 8;
    const int baseA1 = (256 + wv * 64) * 8;
    const int baseB  = (wv * 64) * 8;

    // read-side swizzle: slot = lg ^ ((row>>1)&3); all row-bases are 0 mod 8 rows
    int swz = (lg ^ ((lr >> 1) & 3)) * 8;

    // prologue: stage tile 0 into buf 0
    load_lds16(gA0, &ldsA[0][baseA0]);
    load_lds16(gA1, &ldsA[0][baseA1]);
    load_lds16(gB,  &ldsB[0][baseB]);
    __syncthreads();

    int cur = 0;
    for (int t = 0; t < KITERS; ++t) {
        // stage next tile into the other buffer (overlaps with this tile's MFMA)
        if (t + 1 < KITERS) {
            int k0 = (t + 1) * BK;
            load_lds16(gA0 + k0, &ldsA[cur ^ 1][baseA0]);
            load_lds16(gA1 + k0, &ldsA[cur ^ 1][baseA1]);
            load_lds16(gB  + k0, &ldsB[cur ^ 1][baseB]);
        }
        const unsigned short* bA = ldsA[cur];
        const unsigned short* bB = ldsB[cur];
        bf16x8 af[4], bg[2];
#pragma unroll
        for (int i = 0; i < 4; ++i)
            af[i] = *(const bf16x8*)&bA[(wm * 64 + i * 16 + lr) * BK + swz];
#pragma unroll
        for (int j = 0; j < 2; ++j)
            bg[j] = *(const bf16x8*)&bB[(wn * 32 + j * 16 + lr) * BK + swz];
#pragma unroll
        for (int i = 0; i < 4; ++i)
#pragma unroll
            for (int j = 0; j < 2; ++j)
                acc[i][j] = __builtin_amdgcn_mfma_f32_16x16x32_bf16(af[i], bg[j], acc[i][j], 0, 0, 0);
        __syncthreads();   // drains stage (vmcnt) + all waves done reading buf[cur]
        cur ^= 1;
    }

    // ---- fused epilogue: h = sigmoid(acc + b1); pt[j][t] = sum_m h * W2d[m][t] ----
    // C/D layout: col(n) = lane&15, row(m) = (lane>>4)*4 + reg   [m89-verified]
    float pt[2][NTGT];
#pragma unroll
    for (int j = 0; j < 2; ++j)
#pragma unroll
        for (int t = 0; t < NTGT; ++t) pt[j][t] = 0.f;

#pragma unroll
    for (int i = 0; i < 4; ++i) {
#pragma unroll
        for (int r = 0; r < 4; ++r) {
            int ml = wm * 64 + i * 16 + lg * 4 + r;
            float bn = s_b1[ml];
#pragma unroll
            for (int j = 0; j < 2; ++j) {
                float h = 1.f / (1.f + __expf(-(acc[i][j][r] + bn)));
#pragma unroll
                for (int t = 0; t < NTGT; ++t)
                    pt[j][t] += h * s_w2[ml][t];
            }
        }
    }
    // reduce over lg (lanes lr+16*lg share the same n column)
#pragma unroll
    for (int j = 0; j < 2; ++j)
#pragma unroll
        for (int t = 0; t < NTGT; ++t) {
            float val = pt[j][t];
            val += __shfl_xor(val, 16, 64);
            val += __shfl_xor(val, 32, 64);
            pt[j][t] = val;
        }
    if (lg == 0) {
#pragma unroll
        for (int j = 0; j < 2; ++j) {
            int nl = wn * 32 + j * 16 + lr;
#pragma unroll
            for (int t = 0; t < NTGT; ++t)
                s_pt[wm][nl][t] = pt[j][t];
        }
    }
    __syncthreads();
    // partial[mt][n][t], 64 n x 8 t per block
    for (int idx = tid; idx < BN * NTGT; idx += 256) {
        int nl = idx >> 3, t = idx & 7;
        partial[((size_t)mt * BATCH + (n0 + nl)) * NTGT + t] = s_pt[0][nl][t] + s_pt[1][nl][t];
    }
}

// out[b][t] = b2[t] + sum_mt partial[mt][b][t]
__global__ void k_reduce(const float* __restrict__ partial, const float* __restrict__ b2,
                         float* __restrict__ out) {
    int i = blockIdx.x * blockDim.x + threadIdx.x;  // 32768
    float v = b2[i & 7];
#pragma unroll
    for (int c = 0; c < 8; ++c) v += partial[(size_t)c * BATCH * NTGT + i];
    out[i] = v;
}

extern "C" void kernel_launch(void* const* d_in, const int* in_sizes, int n_in,
                              void* d_out, int out_size, void* d_ws, size_t ws_size,
                              hipStream_t stream) {
    (void)in_sizes; (void)n_in; (void)out_size; (void)ws_size;
    const float* x   = (const float*)d_in[0];
    const float* w1  = (const float*)d_in[1];
    const float* b1  = (const float*)d_in[2];
    const float* w2  = (const float*)d_in[3];
    const float* b2  = (const float*)d_in[4];
    const int*   c1o = (const int*)d_in[5];
    const int*   c1i = (const int*)d_in[6];
    const int*   c2o = (const int*)d_in[7];
    const int*   c2i = (const int*)d_in[8];
    float* out = (float*)d_out;

    char* ws = (char*)d_ws;
    float*          W1f  = (float*)(ws + OFF_W1F);
    float*          W2d  = (float*)(ws + OFF_W2D);
    unsigned short* W1b  = (unsigned short*)(ws + OFF_W1B);
    unsigned short* xb   = (unsigned short*)(ws + OFF_XB);
    float*          part = (float*)(ws + OFF_PART);

    // zero W1f + W2d with a custom vectorized kernel
    k_zero4<<<ZERO_FLOAT4 / 256, 256, 0, stream>>>((float4*)ws);

    // dense weight build
    k_build<<<(NNZ1 + NNZ2) / 256, 256, 0, stream>>>(w1, c1o, c1i, w2, c2o, c2i, W1f, W2d);

    // fp32 -> bf16 for MFMA operands
    k_convert<<<(NNEUR * NFEAT / 4 + BATCH * NFEAT / 4) / 256, 256, 0, stream>>>(W1f, x, W1b, xb);

    // layer 1 GEMM + bias + sigmoid + layer-2 partials, all fused
    k_gemm<<<(NNEUR / BM) * (BATCH / BN), 256, 0, stream>>>(W1b, xb, b1, W2d, part);

    // final reduce over the 8 m-tiles
    k_reduce<<<BATCH * NTGT / 256, 256, 0, stream>>>(part, b2, out);
}